// Round 10
// baseline (518.043 us; speedup 1.0000x reference)
//
#include <hip/hip_runtime.h>
#include <math.h>

typedef __bf16 bf16;
typedef __bf16 bf16x8 __attribute__((ext_vector_type(8)));
typedef float floatx4 __attribute__((ext_vector_type(4)));
typedef unsigned int u32;

#define MFMA16(a, b, c) __builtin_amdgcn_mfma_f32_16x16x32_bf16((a), (b), (c), 0, 0, 0)

static constexpr int NROWS = 8192;
static constexpr int DCH = 512;
static constexpr int QTILE = 64;                 // q rows per block
static constexpr int KTILE = 512;                // K rows per iteration (16 waves x 32 rows, no dup)
static constexpr int NITER = NROWS / KTILE;      // 16 — full K range per block
// 1/sqrt(512) * log2(e): folded into Q so phase A is exp2f(s) directly
static constexpr float PRESCALE = 0.0637587130f;

// Blocked layout: X_blk[r/16][c/32][16][32] bf16 — 16x32 tile = 1KB contiguous;
// MFMA frag load = lane 16B at tile + lm*32 + (lane>>4)*8, fully coalesced.

// async global->LDS, 16B per lane. LDS dest = wave-uniform base + lane*16 (linear).
__device__ __forceinline__ void async16(bf16* lds, const bf16* g) {
    __builtin_amdgcn_global_load_lds(
        (const __attribute__((address_space(1))) u32*)(const void*)g,
        (__attribute__((address_space(3))) u32*)(void*)lds, 16, 0, 0);
}

// ---------------- fp32 -> bf16 blocked convert ----------------
__device__ __forceinline__ void cvt_body(const float* __restrict__ in, bf16* __restrict__ out,
                                         int C, int i, float scale) {
    int c8 = i % (C >> 3);
    int r = i / (C >> 3);
    float4 v0 = ((const float4*)in)[i * 2];
    float4 v1 = ((const float4*)in)[i * 2 + 1];
    bf16x8 o;
    o[0] = (bf16)(v0.x * scale); o[1] = (bf16)(v0.y * scale);
    o[2] = (bf16)(v0.z * scale); o[3] = (bf16)(v0.w * scale);
    o[4] = (bf16)(v1.x * scale); o[5] = (bf16)(v1.y * scale);
    o[6] = (bf16)(v1.z * scale); o[7] = (bf16)(v1.w * scale);
    int nkb = C >> 5;
    size_t e = ((size_t)(r >> 4) * nkb + (c8 >> 2)) * 512 + (r & 15) * 32 + (c8 & 3) * 8;
    *(bf16x8*)(out + e) = o;
}

// merged 3-matrix convert (same shape), selects by blockIdx.y
__global__ void cvt3_blk_kernel(const float* __restrict__ i0, const float* __restrict__ i1,
                                const float* __restrict__ i2,
                                bf16* __restrict__ o0, bf16* __restrict__ o1, bf16* __restrict__ o2,
                                int C, int n8, float s0, float s1, float s2) {
    int i = blockIdx.x * blockDim.x + threadIdx.x;
    if (i >= n8) return;
    const float* in;
    bf16* out;
    float sc;
    if (blockIdx.y == 0)      { in = i0; out = o0; sc = s0; }
    else if (blockIdx.y == 1) { in = i1; out = o1; sc = s1; }
    else                      { in = i2; out = o2; sc = s2; }
    cvt_body(in, out, C, i, sc);
}

// all 5 weight matrices in ONE launch (segments in n8 units; v10 — fewer dispatches)
__global__ void cvt_weights_kernel(const float* __restrict__ q_w, const float* __restrict__ k1_w,
                                   const float* __restrict__ k2_w, const float* __restrict__ v_w,
                                   const float* __restrict__ c1_w,
                                   bf16* __restrict__ qwb, bf16* __restrict__ k1wb,
                                   bf16* __restrict__ k2wb, bf16* __restrict__ vwb,
                                   bf16* __restrict__ c1wb) {
    int i = blockIdx.x * blockDim.x + threadIdx.x;
    // [0,32768): q_w  [32768,65536): k1_w  [65536,98304): k2_w
    // [98304,196608): v_w (C=1536)  [196608,262144): c1_w (C=1024)
    if (i < 32768)        cvt_body(q_w,  qwb,  512,  i,          PRESCALE);
    else if (i < 65536)   cvt_body(k1_w, k1wb, 512,  i - 32768,  1.f);
    else if (i < 98304)   cvt_body(k2_w, k2wb, 512,  i - 65536,  1.f);
    else if (i < 196608)  cvt_body(v_w,  vwb,  1536, i - 98304,  1.f);
    else if (i < 262144)  cvt_body(c1_w, c1wb, 1024, i - 196608, 1.f);
}

// ---------------- merged projection GEMM: 7 projections via blockIdx.z ----------------
// m97-style LDS staging. Z1/Z2 shared-subterm split: Z1 = sp@W1 + om1@W2,
// Z2 = sp@W1 + om2@W2 share sp@W1; T0 = sp@W1 + bias computed once (z=6);
// z=4/5 compute only om1@W2 / om2@W2 (bscale=0). gate_mix sums T0+Z* in f32.
__launch_bounds__(256, 4)
__global__ void proj_gemm(const bf16* __restrict__ spb, const bf16* __restrict__ om1b,
                          const bf16* __restrict__ om2b,
                          const bf16* __restrict__ qwb, const bf16* __restrict__ k1wb,
                          const bf16* __restrict__ k2wb, const bf16* __restrict__ vwb,
                          const bf16* __restrict__ c1wb,
                          const float* __restrict__ q_b, const float* __restrict__ k1_b,
                          const float* __restrict__ k2_b, const float* __restrict__ v_b,
                          const float* __restrict__ c1_b,
                          bf16* __restrict__ Q, bf16* __restrict__ K1, bf16* __restrict__ K2,
                          bf16* __restrict__ Vt, bf16* __restrict__ Z1, bf16* __restrict__ Z2,
                          bf16* __restrict__ T0) {
    __shared__ bf16 smA[16 * 512];   // 16 KB: 16 tiles of [16][32]
    __shared__ bf16 smB[16 * 512];   // 16 KB

    const bf16* As[3] = {nullptr, nullptr, nullptr};
    int wofs[3] = {0, 0, 0};
    int nchunk = 1, ldw = 512, mode = 0;   // 0: blocked, 1: blocked-trans (Vt), 2: row-major
    float bscale = 1.f;
    const bf16* W = nullptr;
    const float* bias = nullptr;
    bf16* out = nullptr;
    switch (blockIdx.z) {
        case 0: As[0] = spb;  W = qwb;  bias = q_b;  out = Q;  bscale = PRESCALE; break;
        case 1: As[0] = om1b; W = k1wb; bias = k1_b; out = K1; break;
        case 2: As[0] = om2b; W = k2wb; bias = k2_b; out = K2; break;
        case 3: As[0] = spb; As[1] = om1b; As[2] = om2b; nchunk = 3; W = vwb; ldw = 1536;
                wofs[1] = 512; wofs[2] = 1024; bias = v_b; out = Vt; mode = 1; break;
        case 4: As[0] = om1b; W = c1wb; ldw = 1024; wofs[0] = 512;
                bias = c1_b; bscale = 0.f; out = Z1; mode = 2; break;   // om1 @ W2
        case 5: As[0] = om2b; W = c1wb; ldw = 1024; wofs[0] = 512;
                bias = c1_b; bscale = 0.f; out = Z2; mode = 2; break;   // om2 @ W2
        default: As[0] = spb; W = c1wb; ldw = 1024; wofs[0] = 0;
                bias = c1_b; bscale = 1.f; out = T0; mode = 2; break;   // sp @ W1 + b
    }

    const int lane = threadIdx.x & 63;
    const int wv = threadIdx.x >> 6;
    const int m0 = blockIdx.y * 128 + (wv >> 1) * 64;
    const int n0 = blockIdx.x * 128 + (wv & 1) * 64;
    const int m0blk = blockIdx.y * 8;        // A super-row base of this block
    const int n0blk = blockIdx.x * 8;        // W super-row base of this block
    const int lm = lane & 15;
    const int r0 = (lane >> 4) * 4;
    const int nkbW = ldw >> 5;
    // frag-read swizzle (identical to attn Qs): chunk = (lane>>4) ^ ((lm>>1)&3)
    const int swz8 = (((lane >> 4) ^ ((lm >> 1) & 3))) * 8;
    // staging source mapping: lane covers LDS (row=lane>>2, slot=lane&3);
    // source chunk = slot ^ ((row>>1)&3) so that swizzled reads invert it.
    const int lrow = lane >> 2;
    const int lsrc8 = ((lane & 3) ^ ((lane >> 3) & 3)) * 8;
    const int srw_m = (wv >> 1) * 4;         // wave's A super-row base within block
    const int srw_n = (wv & 1) * 4;

    floatx4 acc[4][4];
    #pragma unroll
    for (int mt = 0; mt < 4; ++mt)
        #pragma unroll
        for (int nt = 0; nt < 4; ++nt)
            acc[mt][nt] = (floatx4){0.f, 0.f, 0.f, 0.f};

    for (int c = 0; c < nchunk; ++c) {
        const bf16* __restrict__ A = As[c];
        const int wo = wofs[c];
        for (int kk = 0; kk < 512; kk += 64) {
            // stage A[128x64] + B[128x64]: each wave 4 tiles of each (1KB/call)
            #pragma unroll
            for (int j = 0; j < 4; ++j) {
                int t = wv * 4 + j;          // tile = sr*2 + kb
                int sr = t >> 1, kb = t & 1;
                const bf16* srcA = A + ((size_t)(m0blk + sr) * 16 + (kk >> 5) + kb) * 512
                                     + lrow * 32 + lsrc8;
                async16(smA + t * 512, srcA);
                const bf16* srcB = W + ((size_t)(n0blk + sr) * nkbW + ((wo + kk) >> 5) + kb) * 512
                                     + lrow * 32 + lsrc8;
                async16(smB + t * 512, srcB);
            }
            __syncthreads();   // compiler drains vmcnt before s_barrier
            #pragma unroll
            for (int kk2 = 0; kk2 < 2; ++kk2) {
                bf16x8 a[4], b[4];
                #pragma unroll
                for (int mt = 0; mt < 4; ++mt)
                    a[mt] = *(const bf16x8*)(smA + ((srw_m + mt) * 2 + kk2) * 512 + lm * 32 + swz8);
                #pragma unroll
                for (int nt = 0; nt < 4; ++nt)
                    b[nt] = *(const bf16x8*)(smB + ((srw_n + nt) * 2 + kk2) * 512 + lm * 32 + swz8);
                #pragma unroll
                for (int mt = 0; mt < 4; ++mt)
                    #pragma unroll
                    for (int nt = 0; nt < 4; ++nt)
                        acc[mt][nt] = MFMA16(a[mt], b[nt], acc[mt][nt]);
            }
            __syncthreads();
        }
    }

    #pragma unroll
    for (int mt = 0; mt < 4; ++mt)
        #pragma unroll
        for (int nt = 0; nt < 4; ++nt)
            #pragma unroll
            for (int i = 0; i < 4; ++i) {
                int m = m0 + mt * 16 + r0 + i;
                int n = n0 + nt * 16 + lm;
                float v = acc[mt][nt][i] + bias[n] * bscale;
                if (mode == 0)
                    out[((size_t)(m >> 4) * 16 + (n >> 5)) * 512 + (m & 15) * 32 + (n & 31)] = (bf16)v;
                else if (mode == 1)
                    out[((size_t)(n >> 4) * 256 + (m >> 5)) * 512 + (n & 15) * 32 + (m & 31)] = (bf16)v;
                else
                    out[(size_t)m * 512 + n] = (bf16)v;
            }
}

// ---------------- fused single-attention, 64-row q-tile, KTILE=512 (v8, verified 329-332us) ----------------
// block = (qb 0..127, att 0..1), 1024 thr / 16 waves, full K per block.
// KTILE=512: wave ksl=wv owns K rows [kt+ksl*32,+32) — 16x32 = 512, each K row
// read by EXACTLY ONE wave. Phase A: S[64q x 32k] per wave — Q-frags (64) reused
// across both K row-tiles. P single buffer [4 mt][16 ksl][16][32] = 64 KB;
// A;bar;B;bar. Registers: ~64 VGPR + ~56 AGPR ≈ 120 <= 128/wave cap at 16 waves.
// v6/v9 lesson: role-specialized waves (consumer 64-acc + producer peak) exceed
// the 128-reg cap of 1024-thr blocks and spill — do NOT re-attempt.
// Pipe model: MFMA 132us, LDS-read 164us, L2-stream 119us; A;bar;B serializes
// the phase maxima -> 332us. Cross-phase overlap is capacity/register-blocked
// (P dbuf = 192KB LDS; wave-spec spills) — measured limit of this design space.
__launch_bounds__(1024, 4)
__global__ void attn_kernel(const bf16* __restrict__ Q, const bf16* __restrict__ K1g,
                            const bf16* __restrict__ K2g, const bf16* __restrict__ Vt,
                            bf16* __restrict__ On) {
    __shared__ bf16 Qs[64 * 512];            // 64 KB; reused as epilogue staging
    __shared__ bf16 P[4 * 16 * 512];         // [mt4][ksl16][16][32] = 64 KB, single buffer
    __shared__ float lsum[64];

    const int tid = threadIdx.x;
    const int lane = tid & 63;
    const int wv = tid >> 6;                 // 0..15
    const int bid = blockIdx.x;
    const int att = bid & 1;                 // attention index (XCD-specialized via RR)
    const int q0 = (bid >> 1) * QTILE;
    const int lm = lane & 15;
    const int lk8 = (lane >> 4) * 8;
    const int r0 = (lane >> 4) * 4;
    const int ciq8 = ((lane >> 4) ^ ((lm >> 1) & 3)) * 8;  // swizzled LDS frag chunk

    // stage Q tile (4 blocked super-rows = 64 KB contiguous), swizzle into LDS
    {
        const bf16* Qg = Q + (size_t)(q0 >> 4) * (16 * 512);
        #pragma unroll
        for (int j = 0; j < 4; ++j) {
            int ch = tid + 1024 * j;
            bf16x8 v = *(const bf16x8*)(Qg + ch * 8);
            int r = (ch >> 2) & 15;
            int ci = ch & 3;
            int dst = (ch & ~3) * 8 + (ci ^ ((r >> 1) & 3)) * 8;
            *(bf16x8*)(Qs + dst) = v;
        }
    }
    if (tid < 64) lsum[tid] = 0.f;
    __syncthreads();

    const bf16* __restrict__ Kg = att ? K2g : K1g;
    const int ksl = wv;                      // phase-A 32-row K slice (0..15)
    const int d0 = wv * 32;                  // phase-B d-slice

    floatx4 O[4][2];                         // [mt][nt] — 32 acc
    #pragma unroll
    for (int mt = 0; mt < 4; ++mt)
        #pragma unroll
        for (int nt = 0; nt < 2; ++nt)
            O[mt][nt] = (floatx4){0.f, 0.f, 0.f, 0.f};

    float lrs[4][4];                         // partial softmax sums
    #pragma unroll
    for (int mt = 0; mt < 4; ++mt)
        #pragma unroll
        for (int i = 0; i < 4; ++i) lrs[mt][i] = 0.f;

    auto phaseA = [&](int kt) {
        floatx4 s[4][2];                     // [mt][kf] — 32 acc, live in A only
        #pragma unroll
        for (int mt = 0; mt < 4; ++mt) {
            s[mt][0] = (floatx4){0.f, 0.f, 0.f, 0.f};
            s[mt][1] = (floatx4){0.f, 0.f, 0.f, 0.f};
        }
        const bf16* Kp = Kg + ((size_t)((kt >> 4) + ksl * 2) * 16) * 512 + lm * 32 + lk8;
        #pragma unroll
        for (int kb = 0; kb < 16; ++kb) {
            bf16x8 b0 = *(const bf16x8*)(Kp + kb * 512);
            bf16x8 b1 = *(const bf16x8*)(Kp + (16 + kb) * 512);
            #pragma unroll
            for (int mt = 0; mt < 4; ++mt) {
                bf16x8 a = *(const bf16x8*)(Qs + (mt * 16 + kb) * 512 + lm * 32 + ciq8);
                s[mt][0] = MFMA16(a, b0, s[mt][0]);
                s[mt][1] = MFMA16(a, b1, s[mt][1]);
            }
        }
        #pragma unroll
        for (int mt = 0; mt < 4; ++mt) {
            bf16* pt = P + ((mt * 16 + ksl) * 512);
            #pragma unroll
            for (int kf = 0; kf < 2; ++kf)
                #pragma unroll
                for (int i = 0; i < 4; ++i) {
                    float e = exp2f(s[mt][kf][i]);   // Q pre-scaled: exp(logit/sqrt(512))
                    int r = r0 + i;
                    int ci = (kf * 2 + (lm >> 3)) ^ ((r >> 1) & 3);
                    pt[r * 32 + ci * 8 + (lm & 7)] = (bf16)e;
                    lrs[mt][i] += e;
                }
        }
    };

    auto phaseB = [&](int kt) {
        #pragma unroll
        for (int kk2 = 0; kk2 < 16; ++kk2) {
            bf16x8 p[4], bv[2];
            #pragma unroll
            for (int mt = 0; mt < 4; ++mt)
                p[mt] = *(const bf16x8*)(P + ((mt * 16 + kk2) * 512) + lm * 32 + ciq8);
            #pragma unroll
            for (int nt = 0; nt < 2; ++nt)
                bv[nt] = *(const bf16x8*)(Vt + ((size_t)((d0 >> 4) + nt) * 256 + (kt >> 5) + kk2) * 512
                                            + lm * 32 + lk8);
            #pragma unroll
            for (int mt = 0; mt < 4; ++mt)
                #pragma unroll
                for (int nt = 0; nt < 2; ++nt)
                    O[mt][nt] = MFMA16(p[mt], bv[nt], O[mt][nt]);
        }
    };

    for (int it = 0; it < NITER; ++it) {
        phaseA(it * KTILE);
        __syncthreads();                     // P complete
        phaseB(it * KTILE);
        __syncthreads();                     // P consumed, safe to overwrite
    }

    // one-time lsum reduction: over 16 lm-lanes (shuffle) then 16 ksl-waves (LDS atomic)
    #pragma unroll
    for (int mt = 0; mt < 4; ++mt)
        #pragma unroll
        for (int i = 0; i < 4; ++i) {
            float v = lrs[mt][i];
            v += __shfl_xor(v, 1); v += __shfl_xor(v, 2);
            v += __shfl_xor(v, 4); v += __shfl_xor(v, 8);
            if (lm == 0) atomicAdd(&lsum[mt * 16 + r0 + i], v);
        }
    __syncthreads();

    // epilogue: normalize by exact denom, stage bf16 via LDS for full-line stores
    #pragma unroll
    for (int mt = 0; mt < 4; ++mt)
        #pragma unroll
        for (int nt = 0; nt < 2; ++nt)
            #pragma unroll
            for (int i = 0; i < 4; ++i) {
                int row = mt * 16 + r0 + i;
                int c = d0 + nt * 16 + lm;
                int c8s = ((c >> 3) ^ ((row >> 2) & 3)) * 8;  // chunk swizzle vs quad rows
                Qs[row * 512 + c8s + (c & 7)] = (bf16)(O[mt][nt][i] / lsum[row]);
            }
    __syncthreads();
    {
        bf16* Op = On + (size_t)att * NROWS * 512 + (size_t)q0 * 512;
        #pragma unroll
        for (int j = 0; j < 4; ++j) {
            int ch = tid + 1024 * j;
            int r = ch >> 6;
            int c8 = ch & 63;
            *(bf16x8*)(Op + ch * 8) = *(const bf16x8*)(Qs + r * 512 + ((c8 ^ ((r >> 2) & 3)) * 8));
        }
    }
}

// ---------------- gate + mix: out = w*attn1 + (1-w)*attn2 (T0 = sp@W1 shared term) ----------------
__global__ void gate_mix_kernel(const bf16* __restrict__ On, const bf16* __restrict__ Z1,
                                const bf16* __restrict__ Z2, const bf16* __restrict__ T0,
                                float* __restrict__ out, int n4) {
    typedef __bf16 bf16x4v __attribute__((ext_vector_type(4)));
    int i = blockIdx.x * blockDim.x + threadIdx.x;
    if (i >= n4) return;
    const size_t NM = (size_t)NROWS * DCH;
    bf16x4v o1v = ((const bf16x4v*)On)[i];
    bf16x4v o2v = ((const bf16x4v*)(On + NM))[i];
    bf16x4v z1v = ((const bf16x4v*)Z1)[i];
    bf16x4v z2v = ((const bf16x4v*)Z2)[i];
    bf16x4v t0v = ((const bf16x4v*)T0)[i];
    float4 r;
    float* rp = (float*)&r;
    #pragma unroll
    for (int j = 0; j < 4; ++j) {
        float t0 = (float)t0v[j];
        float g1 = 1.f / (1.f + __expf(-(t0 + (float)z1v[j])));
        float g2 = 1.f / (1.f + __expf(-(t0 + (float)z2v[j])));
        float w = 1.f / (1.f + __expf(-(g1 - g2)));   // softmax over 2-stack
        rp[j] = w * (float)o1v[j] + (1.f - w) * (float)o2v[j];
    }
    ((float4*)out)[i] = r;
}

// ---------------- host launch ----------------
extern "C" void kernel_launch(void* const* d_in, const int* in_sizes, int n_in,
                              void* d_out, int out_size, void* d_ws, size_t ws_size,
                              hipStream_t stream) {
    const float* sp   = (const float*)d_in[0];
    const float* om1  = (const float*)d_in[1];
    const float* om2  = (const float*)d_in[2];
    const float* q_w  = (const float*)d_in[3];
    const float* q_b  = (const float*)d_in[4];
    const float* k1_w = (const float*)d_in[5];
    const float* k1_b = (const float*)d_in[6];
    const float* k2_w = (const float*)d_in[7];
    const float* k2_b = (const float*)d_in[8];
    const float* v_w  = (const float*)d_in[9];
    const float* v_b  = (const float*)d_in[10];
    const float* c1_w = (const float*)d_in[11];
    const float* c1_b = (const float*)d_in[12];
    float* out = (float*)d_out;

    char* ws = (char*)d_ws;
    size_t off = 0;
    auto alloc = [&](size_t bytes) -> void* {
        void* p = ws + off;
        off += (bytes + 255) & ~(size_t)255;
        return p;
    };
    const size_t NM = (size_t)NROWS * DCH;

    // persistent region: blocked projections + Z1/Z2/T0 + normalized attn outputs
    bf16* Q    = (bf16*)alloc(NM * 2);
    bf16* K1   = (bf16*)alloc(NM * 2);
    bf16* K2   = (bf16*)alloc(NM * 2);
    bf16* Vt   = (bf16*)alloc(NM * 2);
    bf16* Z1   = (bf16*)alloc(NM * 2);
    bf16* Z2   = (bf16*)alloc(NM * 2);
    bf16* T0   = (bf16*)alloc(NM * 2);
    bf16* On   = (bf16*)alloc((size_t)2 * NM * 2);   // [attn][8192][512] bf16 normalized

    // temp region (dead after proj)
    bf16* spb  = (bf16*)alloc(NM * 2);
    bf16* om1b = (bf16*)alloc(NM * 2);
    bf16* om2b = (bf16*)alloc(NM * 2);
    bf16* qwb  = (bf16*)alloc(512 * 512 * 2);
    bf16* k1wb = (bf16*)alloc(512 * 512 * 2);
    bf16* k2wb = (bf16*)alloc(512 * 512 * 2);
    bf16* vwb  = (bf16*)alloc(512 * 1536 * 2);
    bf16* c1wb = (bf16*)alloc(512 * 1024 * 2);

    // inputs: 3 matrices of [8192,512] in one launch
    {
        int n8 = NROWS * 512 / 8;
        dim3 g((n8 + 255) / 256, 3);
        cvt3_blk_kernel<<<g, 256, 0, stream>>>(sp, om1, om2, spb, om1b, om2b, 512, n8,
                                               1.f, 1.f, 1.f);
    }
    // all 5 weight matrices in one launch (262144 n8-units total)
    cvt_weights_kernel<<<262144 / 256, 256, 0, stream>>>(q_w, k1_w, k2_w, v_w, c1_w,
                                                         qwb, k1wb, k2wb, vwb, c1wb);

    dim3 pgrid(512 / 128, NROWS / 128, 7);
    proj_gemm<<<pgrid, 256, 0, stream>>>(spb, om1b, om2b, qwb, k1wb, k2wb, vwb, c1wb,
                                         q_b, k1_b, k2_b, v_b, c1_b,
                                         Q, K1, K2, Vt, Z1, Z2, T0);

    // fused attention: 256 blocks = (128 q-tiles x 2 attns), 16 waves each, full K
    attn_kernel<<<(NROWS / QTILE) * 2, 1024, 0, stream>>>(Q, K1, K2, Vt, On);

    int n4 = (int)(NM / 4);
    gate_mix_kernel<<<(n4 + 255) / 256, 256, 0, stream>>>(On, Z1, Z2, T0, out, n4);
}

// Round 12
// 471.732 us; speedup vs baseline: 1.0982x; 1.0982x over previous
//
#include <hip/hip_runtime.h>
#include <math.h>

typedef __bf16 bf16;
typedef __bf16 bf16x8 __attribute__((ext_vector_type(8)));
typedef float floatx4 __attribute__((ext_vector_type(4)));
typedef unsigned int u32;

#define MFMA16(a, b, c) __builtin_amdgcn_mfma_f32_16x16x32_bf16((a), (b), (c), 0, 0, 0)

static constexpr int NROWS = 8192;
static constexpr int DCH = 512;
static constexpr int QTILE = 64;                 // q rows per block
static constexpr int KTILE = 512;                // K rows per iteration (16 waves x 32 rows, no dup)
static constexpr int NITER = NROWS / KTILE;      // 16 — full K range per block
// 1/sqrt(512) * log2(e): folded into Q so phase A is exp2f(s) directly
static constexpr float PRESCALE = 0.0637587130f;

// Blocked layout: X_blk[r/16][c/32][16][32] bf16 — 16x32 tile = 1KB contiguous;
// MFMA frag load = lane 16B at tile + lm*32 + (lane>>4)*8, fully coalesced.

// async global->LDS, 16B per lane. LDS dest = wave-uniform base + lane*16 (linear).
__device__ __forceinline__ void async16(bf16* lds, const bf16* g) {
    __builtin_amdgcn_global_load_lds(
        (const __attribute__((address_space(1))) u32*)(const void*)g,
        (__attribute__((address_space(3))) u32*)(void*)lds, 16, 0, 0);
}

// ---------------- fp32 -> bf16 blocked convert ----------------
__device__ __forceinline__ void cvt_body(const float* __restrict__ in, bf16* __restrict__ out,
                                         int C, int i, float scale) {
    int c8 = i % (C >> 3);
    int r = i / (C >> 3);
    float4 v0 = ((const float4*)in)[i * 2];
    float4 v1 = ((const float4*)in)[i * 2 + 1];
    bf16x8 o;
    o[0] = (bf16)(v0.x * scale); o[1] = (bf16)(v0.y * scale);
    o[2] = (bf16)(v0.z * scale); o[3] = (bf16)(v0.w * scale);
    o[4] = (bf16)(v1.x * scale); o[5] = (bf16)(v1.y * scale);
    o[6] = (bf16)(v1.z * scale); o[7] = (bf16)(v1.w * scale);
    int nkb = C >> 5;
    size_t e = ((size_t)(r >> 4) * nkb + (c8 >> 2)) * 512 + (r & 15) * 32 + (c8 & 3) * 8;
    *(bf16x8*)(out + e) = o;
}

__global__ void cvt_blk_kernel(const float* __restrict__ in, bf16* __restrict__ out,
                               int C, int n8, float scale) {
    int i = blockIdx.x * blockDim.x + threadIdx.x;
    if (i >= n8) return;
    cvt_body(in, out, C, i, scale);
}

// merged 3-matrix convert (same shape), selects by blockIdx.y — fewer dispatches
__global__ void cvt3_blk_kernel(const float* __restrict__ i0, const float* __restrict__ i1,
                                const float* __restrict__ i2,
                                bf16* __restrict__ o0, bf16* __restrict__ o1, bf16* __restrict__ o2,
                                int C, int n8, float s0, float s1, float s2) {
    int i = blockIdx.x * blockDim.x + threadIdx.x;
    if (i >= n8) return;
    const float* in;
    bf16* out;
    float sc;
    if (blockIdx.y == 0)      { in = i0; out = o0; sc = s0; }
    else if (blockIdx.y == 1) { in = i1; out = o1; sc = s1; }
    else                      { in = i2; out = o2; sc = s2; }
    cvt_body(in, out, C, i, sc);
}

// ---------------- merged projection GEMM: 7 projections via blockIdx.z ----------------
// m97-style LDS staging. Z1/Z2 shared-subterm split: Z1 = sp@W1 + om1@W2,
// Z2 = sp@W1 + om2@W2 share sp@W1; T0 = sp@W1 + bias computed once (z=6);
// z=4/5 compute only om1@W2 / om2@W2 (bscale=0). gate_mix sums T0+Z* in f32.
__launch_bounds__(256, 4)
__global__ void proj_gemm(const bf16* __restrict__ spb, const bf16* __restrict__ om1b,
                          const bf16* __restrict__ om2b,
                          const bf16* __restrict__ qwb, const bf16* __restrict__ k1wb,
                          const bf16* __restrict__ k2wb, const bf16* __restrict__ vwb,
                          const bf16* __restrict__ c1wb,
                          const float* __restrict__ q_b, const float* __restrict__ k1_b,
                          const float* __restrict__ k2_b, const float* __restrict__ v_b,
                          const float* __restrict__ c1_b,
                          bf16* __restrict__ Q, bf16* __restrict__ K1, bf16* __restrict__ K2,
                          bf16* __restrict__ Vt, bf16* __restrict__ Z1, bf16* __restrict__ Z2,
                          bf16* __restrict__ T0) {
    __shared__ bf16 smA[16 * 512];   // 16 KB: 16 tiles of [16][32]
    __shared__ bf16 smB[16 * 512];   // 16 KB

    const bf16* As[3] = {nullptr, nullptr, nullptr};
    int wofs[3] = {0, 0, 0};
    int nchunk = 1, ldw = 512, mode = 0;   // 0: blocked, 1: blocked-trans (Vt), 2: row-major
    float bscale = 1.f;
    const bf16* W = nullptr;
    const float* bias = nullptr;
    bf16* out = nullptr;
    switch (blockIdx.z) {
        case 0: As[0] = spb;  W = qwb;  bias = q_b;  out = Q;  bscale = PRESCALE; break;
        case 1: As[0] = om1b; W = k1wb; bias = k1_b; out = K1; break;
        case 2: As[0] = om2b; W = k2wb; bias = k2_b; out = K2; break;
        case 3: As[0] = spb; As[1] = om1b; As[2] = om2b; nchunk = 3; W = vwb; ldw = 1536;
                wofs[1] = 512; wofs[2] = 1024; bias = v_b; out = Vt; mode = 1; break;
        case 4: As[0] = om1b; W = c1wb; ldw = 1024; wofs[0] = 512;
                bias = c1_b; bscale = 0.f; out = Z1; mode = 2; break;   // om1 @ W2
        case 5: As[0] = om2b; W = c1wb; ldw = 1024; wofs[0] = 512;
                bias = c1_b; bscale = 0.f; out = Z2; mode = 2; break;   // om2 @ W2
        default: As[0] = spb; W = c1wb; ldw = 1024; wofs[0] = 0;
                bias = c1_b; bscale = 1.f; out = T0; mode = 2; break;   // sp @ W1 + b
    }

    const int lane = threadIdx.x & 63;
    const int wv = threadIdx.x >> 6;
    const int m0 = blockIdx.y * 128 + (wv >> 1) * 64;
    const int n0 = blockIdx.x * 128 + (wv & 1) * 64;
    const int m0blk = blockIdx.y * 8;        // A super-row base of this block
    const int n0blk = blockIdx.x * 8;        // W super-row base of this block
    const int lm = lane & 15;
    const int r0 = (lane >> 4) * 4;
    const int nkbW = ldw >> 5;
    // frag-read swizzle (identical to attn Qs): chunk = (lane>>4) ^ ((lm>>1)&3)
    const int swz8 = (((lane >> 4) ^ ((lm >> 1) & 3))) * 8;
    // staging source mapping: lane covers LDS (row=lane>>2, slot=lane&3);
    // source chunk = slot ^ ((row>>1)&3) so that swizzled reads invert it.
    const int lrow = lane >> 2;
    const int lsrc8 = ((lane & 3) ^ ((lane >> 3) & 3)) * 8;
    const int srw_m = (wv >> 1) * 4;         // wave's A super-row base within block
    const int srw_n = (wv & 1) * 4;

    floatx4 acc[4][4];
    #pragma unroll
    for (int mt = 0; mt < 4; ++mt)
        #pragma unroll
        for (int nt = 0; nt < 4; ++nt)
            acc[mt][nt] = (floatx4){0.f, 0.f, 0.f, 0.f};

    for (int c = 0; c < nchunk; ++c) {
        const bf16* __restrict__ A = As[c];
        const int wo = wofs[c];
        for (int kk = 0; kk < 512; kk += 64) {
            // stage A[128x64] + B[128x64]: each wave 4 tiles of each (1KB/call)
            #pragma unroll
            for (int j = 0; j < 4; ++j) {
                int t = wv * 4 + j;          // tile = sr*2 + kb
                int sr = t >> 1, kb = t & 1;
                const bf16* srcA = A + ((size_t)(m0blk + sr) * 16 + (kk >> 5) + kb) * 512
                                     + lrow * 32 + lsrc8;
                async16(smA + t * 512, srcA);
                const bf16* srcB = W + ((size_t)(n0blk + sr) * nkbW + ((wo + kk) >> 5) + kb) * 512
                                     + lrow * 32 + lsrc8;
                async16(smB + t * 512, srcB);
            }
            __syncthreads();   // compiler drains vmcnt before s_barrier
            #pragma unroll
            for (int kk2 = 0; kk2 < 2; ++kk2) {
                bf16x8 a[4], b[4];
                #pragma unroll
                for (int mt = 0; mt < 4; ++mt)
                    a[mt] = *(const bf16x8*)(smA + ((srw_m + mt) * 2 + kk2) * 512 + lm * 32 + swz8);
                #pragma unroll
                for (int nt = 0; nt < 4; ++nt)
                    b[nt] = *(const bf16x8*)(smB + ((srw_n + nt) * 2 + kk2) * 512 + lm * 32 + swz8);
                #pragma unroll
                for (int mt = 0; mt < 4; ++mt)
                    #pragma unroll
                    for (int nt = 0; nt < 4; ++nt)
                        acc[mt][nt] = MFMA16(a[mt], b[nt], acc[mt][nt]);
            }
            __syncthreads();
        }
    }

    #pragma unroll
    for (int mt = 0; mt < 4; ++mt)
        #pragma unroll
        for (int nt = 0; nt < 4; ++nt)
            #pragma unroll
            for (int i = 0; i < 4; ++i) {
                int m = m0 + mt * 16 + r0 + i;
                int n = n0 + nt * 16 + lm;
                float v = acc[mt][nt][i] + bias[n] * bscale;
                if (mode == 0)
                    out[((size_t)(m >> 4) * 16 + (n >> 5)) * 512 + (m & 15) * 32 + (n & 31)] = (bf16)v;
                else if (mode == 1)
                    out[((size_t)(n >> 4) * 256 + (m >> 5)) * 512 + (n & 15) * 32 + (m & 31)] = (bf16)v;
                else
                    out[(size_t)m * 512 + n] = (bf16)v;
            }
}

// ---------------- fused single-attention, 64-row q-tile, KTILE=512 (v8, verified 329-340us) ----------------
// block = (qb 0..127, att 0..1), 1024 thr / 16 waves, full K per block.
// KTILE=512: wave ksl=wv owns K rows [kt+ksl*32,+32) — 16x32 = 512, each K row
// read by EXACTLY ONE wave. Phase A: S[64q x 32k] per wave — Q-frags (64) reused
// across both K row-tiles. P single buffer [4 mt][16 ksl][16][32] = 64 KB;
// A;bar;B;bar. Registers: ~64 VGPR + ~56 AGPR ≈ 120 <= 128/wave cap at 16 waves.
// v6/v9 lesson: role-specialized waves (consumer 64-acc + producer peak) exceed
// the 128-reg cap of 1024-thr blocks and spill — do NOT re-attempt.
// Pipe model: MFMA 132us, LDS-read 164us, L2-stream 119us; A;bar;B serializes
// the phase maxima -> ~332us. Cross-phase overlap is capacity/register-blocked
// (P dbuf = 192KB LDS; wave-spec spills) — measured limit of this design space.
__launch_bounds__(1024, 4)
__global__ void attn_kernel(const bf16* __restrict__ Q, const bf16* __restrict__ K1g,
                            const bf16* __restrict__ K2g, const bf16* __restrict__ Vt,
                            bf16* __restrict__ On) {
    __shared__ bf16 Qs[64 * 512];            // 64 KB; reused as epilogue staging
    __shared__ bf16 P[4 * 16 * 512];         // [mt4][ksl16][16][32] = 64 KB, single buffer
    __shared__ float lsum[64];

    const int tid = threadIdx.x;
    const int lane = tid & 63;
    const int wv = tid >> 6;                 // 0..15
    const int bid = blockIdx.x;
    const int att = bid & 1;                 // attention index (XCD-specialized via RR)
    const int q0 = (bid >> 1) * QTILE;
    const int lm = lane & 15;
    const int lk8 = (lane >> 4) * 8;
    const int r0 = (lane >> 4) * 4;
    const int ciq8 = ((lane >> 4) ^ ((lm >> 1) & 3)) * 8;  // swizzled LDS frag chunk

    // stage Q tile (4 blocked super-rows = 64 KB contiguous), swizzle into LDS
    {
        const bf16* Qg = Q + (size_t)(q0 >> 4) * (16 * 512);
        #pragma unroll
        for (int j = 0; j < 4; ++j) {
            int ch = tid + 1024 * j;
            bf16x8 v = *(const bf16x8*)(Qg + ch * 8);
            int r = (ch >> 2) & 15;
            int ci = ch & 3;
            int dst = (ch & ~3) * 8 + (ci ^ ((r >> 1) & 3)) * 8;
            *(bf16x8*)(Qs + dst) = v;
        }
    }
    if (tid < 64) lsum[tid] = 0.f;
    __syncthreads();

    const bf16* __restrict__ Kg = att ? K2g : K1g;
    const int ksl = wv;                      // phase-A 32-row K slice (0..15)
    const int d0 = wv * 32;                  // phase-B d-slice

    floatx4 O[4][2];                         // [mt][nt] — 32 acc
    #pragma unroll
    for (int mt = 0; mt < 4; ++mt)
        #pragma unroll
        for (int nt = 0; nt < 2; ++nt)
            O[mt][nt] = (floatx4){0.f, 0.f, 0.f, 0.f};

    float lrs[4][4];                         // partial softmax sums
    #pragma unroll
    for (int mt = 0; mt < 4; ++mt)
        #pragma unroll
        for (int i = 0; i < 4; ++i) lrs[mt][i] = 0.f;

    auto phaseA = [&](int kt) {
        floatx4 s[4][2];                     // [mt][kf] — 32 acc, live in A only
        #pragma unroll
        for (int mt = 0; mt < 4; ++mt) {
            s[mt][0] = (floatx4){0.f, 0.f, 0.f, 0.f};
            s[mt][1] = (floatx4){0.f, 0.f, 0.f, 0.f};
        }
        const bf16* Kp = Kg + ((size_t)((kt >> 4) + ksl * 2) * 16) * 512 + lm * 32 + lk8;
        #pragma unroll
        for (int kb = 0; kb < 16; ++kb) {
            bf16x8 b0 = *(const bf16x8*)(Kp + kb * 512);
            bf16x8 b1 = *(const bf16x8*)(Kp + (16 + kb) * 512);
            #pragma unroll
            for (int mt = 0; mt < 4; ++mt) {
                bf16x8 a = *(const bf16x8*)(Qs + (mt * 16 + kb) * 512 + lm * 32 + ciq8);
                s[mt][0] = MFMA16(a, b0, s[mt][0]);
                s[mt][1] = MFMA16(a, b1, s[mt][1]);
            }
        }
        #pragma unroll
        for (int mt = 0; mt < 4; ++mt) {
            bf16* pt = P + ((mt * 16 + ksl) * 512);
            #pragma unroll
            for (int kf = 0; kf < 2; ++kf)
                #pragma unroll
                for (int i = 0; i < 4; ++i) {
                    float e = exp2f(s[mt][kf][i]);   // Q pre-scaled: exp(logit/sqrt(512))
                    int r = r0 + i;
                    int ci = (kf * 2 + (lm >> 3)) ^ ((r >> 1) & 3);
                    pt[r * 32 + ci * 8 + (lm & 7)] = (bf16)e;
                    lrs[mt][i] += e;
                }
        }
    };

    auto phaseB = [&](int kt) {
        #pragma unroll
        for (int kk2 = 0; kk2 < 16; ++kk2) {
            bf16x8 p[4], bv[2];
            #pragma unroll
            for (int mt = 0; mt < 4; ++mt)
                p[mt] = *(const bf16x8*)(P + ((mt * 16 + kk2) * 512) + lm * 32 + ciq8);
            #pragma unroll
            for (int nt = 0; nt < 2; ++nt)
                bv[nt] = *(const bf16x8*)(Vt + ((size_t)((d0 >> 4) + nt) * 256 + (kt >> 5) + kk2) * 512
                                            + lm * 32 + lk8);
            #pragma unroll
            for (int mt = 0; mt < 4; ++mt)
                #pragma unroll
                for (int nt = 0; nt < 2; ++nt)
                    O[mt][nt] = MFMA16(p[mt], bv[nt], O[mt][nt]);
        }
    };

    for (int it = 0; it < NITER; ++it) {
        phaseA(it * KTILE);
        __syncthreads();                     // P complete
        phaseB(it * KTILE);
        __syncthreads();                     // P consumed, safe to overwrite
    }

    // one-time lsum reduction: over 16 lm-lanes (shuffle) then 16 ksl-waves (LDS atomic)
    #pragma unroll
    for (int mt = 0; mt < 4; ++mt)
        #pragma unroll
        for (int i = 0; i < 4; ++i) {
            float v = lrs[mt][i];
            v += __shfl_xor(v, 1); v += __shfl_xor(v, 2);
            v += __shfl_xor(v, 4); v += __shfl_xor(v, 8);
            if (lm == 0) atomicAdd(&lsum[mt * 16 + r0 + i], v);
        }
    __syncthreads();

    // epilogue: normalize by exact denom, stage bf16 via LDS for full-line stores
    #pragma unroll
    for (int mt = 0; mt < 4; ++mt)
        #pragma unroll
        for (int nt = 0; nt < 2; ++nt)
            #pragma unroll
            for (int i = 0; i < 4; ++i) {
                int row = mt * 16 + r0 + i;
                int c = d0 + nt * 16 + lm;
                int c8s = ((c >> 3) ^ ((row >> 2) & 3)) * 8;  // chunk swizzle vs quad rows
                Qs[row * 512 + c8s + (c & 7)] = (bf16)(O[mt][nt][i] / lsum[row]);
            }
    __syncthreads();
    {
        bf16* Op = On + (size_t)att * NROWS * 512 + (size_t)q0 * 512;
        #pragma unroll
        for (int j = 0; j < 4; ++j) {
            int ch = tid + 1024 * j;
            int r = ch >> 6;
            int c8 = ch & 63;
            *(bf16x8*)(Op + ch * 8) = *(const bf16x8*)(Qs + r * 512 + ((c8 ^ ((r >> 2) & 3)) * 8));
        }
    }
}

// ---------------- gate + mix: out = w*attn1 + (1-w)*attn2 (T0 = sp@W1 shared term) ----------------
__global__ void gate_mix_kernel(const bf16* __restrict__ On, const bf16* __restrict__ Z1,
                                const bf16* __restrict__ Z2, const bf16* __restrict__ T0,
                                float* __restrict__ out, int n4) {
    typedef __bf16 bf16x4v __attribute__((ext_vector_type(4)));
    int i = blockIdx.x * blockDim.x + threadIdx.x;
    if (i >= n4) return;
    const size_t NM = (size_t)NROWS * DCH;
    bf16x4v o1v = ((const bf16x4v*)On)[i];
    bf16x4v o2v = ((const bf16x4v*)(On + NM))[i];
    bf16x4v z1v = ((const bf16x4v*)Z1)[i];
    bf16x4v z2v = ((const bf16x4v*)Z2)[i];
    bf16x4v t0v = ((const bf16x4v*)T0)[i];
    float4 r;
    float* rp = (float*)&r;
    #pragma unroll
    for (int j = 0; j < 4; ++j) {
        float t0 = (float)t0v[j];
        float g1 = 1.f / (1.f + __expf(-(t0 + (float)z1v[j])));
        float g2 = 1.f / (1.f + __expf(-(t0 + (float)z2v[j])));
        float w = 1.f / (1.f + __expf(-(g1 - g2)));   // softmax over 2-stack
        rp[j] = w * (float)o1v[j] + (1.f - w) * (float)o2v[j];
    }
    ((float4*)out)[i] = r;
}

// ---------------- host launch ----------------
extern "C" void kernel_launch(void* const* d_in, const int* in_sizes, int n_in,
                              void* d_out, int out_size, void* d_ws, size_t ws_size,
                              hipStream_t stream) {
    const float* sp   = (const float*)d_in[0];
    const float* om1  = (const float*)d_in[1];
    const float* om2  = (const float*)d_in[2];
    const float* q_w  = (const float*)d_in[3];
    const float* q_b  = (const float*)d_in[4];
    const float* k1_w = (const float*)d_in[5];
    const float* k1_b = (const float*)d_in[6];
    const float* k2_w = (const float*)d_in[7];
    const float* k2_b = (const float*)d_in[8];
    const float* v_w  = (const float*)d_in[9];
    const float* v_b  = (const float*)d_in[10];
    const float* c1_w = (const float*)d_in[11];
    const float* c1_b = (const float*)d_in[12];
    float* out = (float*)d_out;

    char* ws = (char*)d_ws;
    size_t off = 0;
    auto alloc = [&](size_t bytes) -> void* {
        void* p = ws + off;
        off += (bytes + 255) & ~(size_t)255;
        return p;
    };
    const size_t NM = (size_t)NROWS * DCH;

    // persistent region: blocked projections + Z1/Z2/T0 + normalized attn outputs
    bf16* Q    = (bf16*)alloc(NM * 2);
    bf16* K1   = (bf16*)alloc(NM * 2);
    bf16* K2   = (bf16*)alloc(NM * 2);
    bf16* Vt   = (bf16*)alloc(NM * 2);
    bf16* Z1   = (bf16*)alloc(NM * 2);
    bf16* Z2   = (bf16*)alloc(NM * 2);
    bf16* T0   = (bf16*)alloc(NM * 2);
    bf16* On   = (bf16*)alloc((size_t)2 * NM * 2);   // [attn][8192][512] bf16 normalized

    // temp region (dead after proj)
    bf16* spb  = (bf16*)alloc(NM * 2);
    bf16* om1b = (bf16*)alloc(NM * 2);
    bf16* om2b = (bf16*)alloc(NM * 2);
    bf16* qwb  = (bf16*)alloc(512 * 512 * 2);
    bf16* k1wb = (bf16*)alloc(512 * 512 * 2);
    bf16* k2wb = (bf16*)alloc(512 * 512 * 2);
    bf16* vwb  = (bf16*)alloc(512 * 1536 * 2);
    bf16* c1wb = (bf16*)alloc(512 * 1024 * 2);

    // inputs: 3 matrices of [8192,512] in one launch
    {
        int n8 = NROWS * 512 / 8;
        dim3 g((n8 + 255) / 256, 3);
        cvt3_blk_kernel<<<g, 256, 0, stream>>>(sp, om1, om2, spb, om1b, om2b, 512, n8,
                                               1.f, 1.f, 1.f);
    }
    // q/k1/k2 weights: 3 matrices of [512,512] in one launch (PRESCALE folded into Q)
    {
        int n8 = 512 * 512 / 8;
        dim3 g((n8 + 255) / 256, 3);
        cvt3_blk_kernel<<<g, 256, 0, stream>>>(q_w, k1_w, k2_w, qwb, k1wb, k2wb, 512, n8,
                                               PRESCALE, 1.f, 1.f);
    }
    cvt_blk_kernel<<<(512 * 1536 / 8 + 255) / 256, 256, 0, stream>>>(v_w, vwb, 1536,
                                                                     512 * 1536 / 8, 1.f);
    cvt_blk_kernel<<<(512 * 1024 / 8 + 255) / 256, 256, 0, stream>>>(c1_w, c1wb, 1024,
                                                                     512 * 1024 / 8, 1.f);

    dim3 pgrid(512 / 128, NROWS / 128, 7);
    proj_gemm<<<pgrid, 256, 0, stream>>>(spb, om1b, om2b, qwb, k1wb, k2wb, vwb, c1wb,
                                         q_b, k1_b, k2_b, v_b, c1_b,
                                         Q, K1, K2, Vt, Z1, Z2, T0);

    // fused attention: 256 blocks = (128 q-tiles x 2 attns), 16 waves each, full K
    attn_kernel<<<(NROWS / QTILE) * 2, 1024, 0, stream>>>(Q, K1, K2, Vt, On);

    int n4 = (int)(NM / 4);
    gate_mix_kernel<<<(n4 + 255) / 256, 256, 0, stream>>>(On, Z1, Z2, T0, out, n4);
}